// Round 1
// baseline (2030.837 us; speedup 1.0000x reference)
//
#include <hip/hip_runtime.h>
#include <math.h>

#define D_MODEL 1024
#define NH 16
#define DK 64
#define SEQ 2048
#define BATCH 2

static constexpr float NEGV = -1e8f;

// ---------------- QKV projection: y = X @ W^T + b ----------------
// X: [M=B*S, D] row-major; W: [O, D] row-major (NT GEMM, dot of rows).
// Output written directly in [B, H, S, DK] layout for the attention phase.
__global__ __launch_bounds__(256) void qkv_gemm(
    const float* __restrict__ X,
    const float* __restrict__ Wq, const float* __restrict__ bq,
    const float* __restrict__ Wk, const float* __restrict__ bk,
    const float* __restrict__ Wv, const float* __restrict__ bv,
    float* __restrict__ Qo, float* __restrict__ Ko, float* __restrict__ Vo)
{
    constexpr int BM = 64, BN = 64, BK = 16, LDP = 68; // LDP=68: pad to break conflicts, keep float4 align
    __shared__ float As[BK][LDP];
    __shared__ float Bs[BK][LDP];

    const int which = blockIdx.z;
    const float* __restrict__ W    = which == 0 ? Wq : (which == 1 ? Wk : Wv);
    const float* __restrict__ bias = which == 0 ? bq : (which == 1 ? bk : bv);
    float* __restrict__ Out        = which == 0 ? Qo : (which == 1 ? Ko : Vo);

    const int m0 = blockIdx.x * BM;
    const int n0 = blockIdx.y * BN;
    const int tid = threadIdx.x;
    const int tx = tid & 15, ty = tid >> 4;
    const int lrow = tid >> 2, lseg = tid & 3; // 64 rows x 4 float4-segments

    float acc[4][4] = {};

    for (int k0 = 0; k0 < D_MODEL; k0 += BK) {
        float4 av = *(const float4*)(X + (size_t)(m0 + lrow) * D_MODEL + k0 + lseg * 4);
        float4 wv = *(const float4*)(W + (size_t)(n0 + lrow) * D_MODEL + k0 + lseg * 4);
        __syncthreads(); // previous iter's LDS reads done
        As[lseg * 4 + 0][lrow] = av.x; As[lseg * 4 + 1][lrow] = av.y;
        As[lseg * 4 + 2][lrow] = av.z; As[lseg * 4 + 3][lrow] = av.w;
        Bs[lseg * 4 + 0][lrow] = wv.x; Bs[lseg * 4 + 1][lrow] = wv.y;
        Bs[lseg * 4 + 2][lrow] = wv.z; Bs[lseg * 4 + 3][lrow] = wv.w;
        __syncthreads();
#pragma unroll
        for (int k = 0; k < BK; k++) {
            float4 a = *(const float4*)&As[k][ty * 4];
            float4 b = *(const float4*)&Bs[k][tx * 4];
            float ar[4] = {a.x, a.y, a.z, a.w};
            float br[4] = {b.x, b.y, b.z, b.w};
#pragma unroll
            for (int i = 0; i < 4; i++)
#pragma unroll
                for (int j = 0; j < 4; j++)
                    acc[i][j] += ar[i] * br[j];
        }
    }

    // epilogue: bias add + scatter to [B,H,S,DK]. n-tile is 64 wide => single head per block.
    const int h = n0 >> 6;
    const int d0 = tx * 4; // d within head
    float4 bw = *(const float4*)(bias + n0 + d0);
#pragma unroll
    for (int i = 0; i < 4; i++) {
        int m = m0 + ty * 4 + i;
        int b_ = m >> 11;      // / SEQ
        int s  = m & (SEQ - 1);
        float4 o;
        o.x = acc[i][0] + bw.x;
        o.y = acc[i][1] + bw.y;
        o.z = acc[i][2] + bw.z;
        o.w = acc[i][3] + bw.w;
        *(float4*)(Out + (((size_t)b_ * NH + h) * SEQ + s) * DK + d0) = o;
    }
}

// ---------------- Flash attention ----------------
// One block per (b, h, 64-row Q tile). K/V tiles of 64 keys staged in LDS.
__global__ __launch_bounds__(256) void attn(
    const float* __restrict__ Qb, const float* __restrict__ Kb,
    const float* __restrict__ Vb, const int* __restrict__ mask,
    float* __restrict__ out)
{
    constexpr int LDP = 68;
    __shared__ float Qs[64][LDP];
    __shared__ float Ks[64][LDP];
    __shared__ float Vs[64][LDP];
    __shared__ float Ps[64][LDP];
    __shared__ float redmax[64][16];
    __shared__ float redsum[64][16];
    __shared__ int   ms[64];

    const int qt = blockIdx.x, h = blockIdx.y, b = blockIdx.z;
    const float* __restrict__ Qp = Qb + (((size_t)b * NH + h) * SEQ + qt * 64) * DK;
    const float* __restrict__ Kp = Kb + ((size_t)b * NH + h) * SEQ * DK;
    const float* __restrict__ Vp = Vb + ((size_t)b * NH + h) * SEQ * DK;
    const int* __restrict__ mp = mask + b * SEQ;

    const int tid = threadIdx.x;
    const int tx = tid & 15, ty = tid >> 4;

    // load Q tile (64x64 floats = 1024 float4, 4 per thread)
#pragma unroll
    for (int t = 0; t < 4; t++) {
        int idx = tid + t * 256;
        int row = idx >> 4, c4 = (idx & 15) * 4;
        *(float4*)&Qs[row][c4] = *(const float4*)(Qp + row * DK + c4);
    }

    float O[4][4] = {};
    float mrow[4], lrow[4];
#pragma unroll
    for (int i = 0; i < 4; i++) { mrow[i] = -INFINITY; lrow[i] = 0.0f; }

    for (int kt = 0; kt < SEQ / 64; kt++) {
        __syncthreads(); // prev iter PV reads done (also covers Q-tile write on iter 0)
#pragma unroll
        for (int t = 0; t < 4; t++) {
            int idx = tid + t * 256;
            int row = idx >> 4, c4 = (idx & 15) * 4;
            *(float4*)&Ks[row][c4] = *(const float4*)(Kp + (size_t)(kt * 64 + row) * DK + c4);
            *(float4*)&Vs[row][c4] = *(const float4*)(Vp + (size_t)(kt * 64 + row) * DK + c4);
        }
        if (tid < 64) ms[tid] = mp[kt * 64 + tid];
        __syncthreads();

        // scores s[i][j] = Q[row] . K[col]
        float s[4][4] = {};
#pragma unroll
        for (int k = 0; k < DK; k += 4) {
            float4 a[4], bb[4];
#pragma unroll
            for (int i = 0; i < 4; i++) a[i] = *(const float4*)&Qs[ty * 4 + i][k];
#pragma unroll
            for (int j = 0; j < 4; j++) bb[j] = *(const float4*)&Ks[tx * 4 + j][k];
#pragma unroll
            for (int i = 0; i < 4; i++)
#pragma unroll
                for (int j = 0; j < 4; j++)
                    s[i][j] += a[i].x * bb[j].x + a[i].y * bb[j].y + a[i].z * bb[j].z + a[i].w * bb[j].w;
        }
        // scale + key mask
#pragma unroll
        for (int j = 0; j < 4; j++) {
            int masked = ms[tx * 4 + j];
#pragma unroll
            for (int i = 0; i < 4; i++)
                s[i][j] = masked ? NEGV : s[i][j] * 0.125f;
        }
        // local row max -> LDS reduce
        float lm[4];
#pragma unroll
        for (int i = 0; i < 4; i++) {
            lm[i] = fmaxf(fmaxf(s[i][0], s[i][1]), fmaxf(s[i][2], s[i][3]));
            redmax[ty * 4 + i][tx] = lm[i];
        }
        __syncthreads();
        float mnew[4], alpha[4];
#pragma unroll
        for (int i = 0; i < 4; i++) {
            float mx = mrow[i];
#pragma unroll
            for (int t = 0; t < 16; t++) mx = fmaxf(mx, redmax[ty * 4 + i][t]);
            mnew[i] = mx;
            alpha[i] = __expf(mrow[i] - mx); // exp(-inf)=0 on first tile
        }
        // p = exp(s - mnew), row partial sums
        float p[4][4], ls[4] = {0, 0, 0, 0};
#pragma unroll
        for (int i = 0; i < 4; i++) {
#pragma unroll
            for (int j = 0; j < 4; j++) {
                p[i][j] = __expf(s[i][j] - mnew[i]);
                ls[i] += p[i][j];
            }
            *(float4*)&Ps[ty * 4 + i][tx * 4] = make_float4(p[i][0], p[i][1], p[i][2], p[i][3]);
            redsum[ty * 4 + i][tx] = ls[i];
        }
        __syncthreads();
#pragma unroll
        for (int i = 0; i < 4; i++) {
            float rs = 0.0f;
#pragma unroll
            for (int t = 0; t < 16; t++) rs += redsum[ty * 4 + i][t];
            lrow[i] = alpha[i] * lrow[i] + rs;
            mrow[i] = mnew[i];
#pragma unroll
            for (int j = 0; j < 4; j++) O[i][j] *= alpha[i];
        }
        // PV: O += P @ V  (k-chunks of 4)
#pragma unroll
        for (int k = 0; k < 64; k += 4) {
            float4 pv[4], vv[4];
#pragma unroll
            for (int i = 0; i < 4; i++) pv[i] = *(const float4*)&Ps[ty * 4 + i][k];
#pragma unroll
            for (int kk = 0; kk < 4; kk++) vv[kk] = *(const float4*)&Vs[k + kk][tx * 4];
#pragma unroll
            for (int i = 0; i < 4; i++) {
                O[i][0] += pv[i].x * vv[0].x + pv[i].y * vv[1].x + pv[i].z * vv[2].x + pv[i].w * vv[3].x;
                O[i][1] += pv[i].x * vv[0].y + pv[i].y * vv[1].y + pv[i].z * vv[2].y + pv[i].w * vv[3].y;
                O[i][2] += pv[i].x * vv[0].z + pv[i].y * vv[1].z + pv[i].z * vv[2].z + pv[i].w * vv[3].z;
                O[i][3] += pv[i].x * vv[0].w + pv[i].y * vv[1].w + pv[i].z * vv[2].w + pv[i].w * vv[3].w;
            }
        }
    }

    // epilogue: normalize and write [B,S,D_MODEL]
#pragma unroll
    for (int i = 0; i < 4; i++) {
        float inv = 1.0f / lrow[i];
        int q = qt * 64 + ty * 4 + i;
        float4 o = make_float4(O[i][0] * inv, O[i][1] * inv, O[i][2] * inv, O[i][3] * inv);
        *(float4*)(out + ((size_t)b * SEQ + q) * D_MODEL + h * DK + tx * 4) = o;
    }
}

extern "C" void kernel_launch(void* const* d_in, const int* in_sizes, int n_in,
                              void* d_out, int out_size, void* d_ws, size_t ws_size,
                              hipStream_t stream)
{
    const float* X  = (const float*)d_in[0];
    const int* mask = (const int*)d_in[1];
    const float* Wq = (const float*)d_in[2];
    const float* bq = (const float*)d_in[3];
    const float* Wk = (const float*)d_in[4];
    const float* bk = (const float*)d_in[5];
    const float* Wv = (const float*)d_in[6];
    const float* bv = (const float*)d_in[7];
    float* out = (float*)d_out;

    const size_t per = (size_t)BATCH * NH * SEQ * DK; // 4M floats = 16 MB
    float* Qb = (float*)d_ws;
    float* Kb = Qb + per;
    float* Vb = Kb + per;

    qkv_gemm<<<dim3((BATCH * SEQ) / 64, D_MODEL / 64, 3), 256, 0, stream>>>(
        X, Wq, bq, Wk, bk, Wv, bv, Qb, Kb, Vb);
    attn<<<dim3(SEQ / 64, NH, BATCH), 256, 0, stream>>>(Qb, Kb, Vb, mask, out);
}

// Round 2
// 247.672 us; speedup vs baseline: 8.1997x; 8.1997x over previous
//
#include <hip/hip_runtime.h>
#include <math.h>

#define D_MODEL 1024
#define NH 16
#define DK 64
#define SEQ 2048
#define BATCH 2
#define MTOT (BATCH * SEQ)

typedef unsigned short u16;
typedef unsigned int u32;
typedef short bf16x8 __attribute__((ext_vector_type(8)));   // 8 bf16 = 4 VGPR (A/B frag)
typedef float f32x4 __attribute__((ext_vector_type(4)));    // C/D frag

static constexpr float NEGV = -1e8f;

__device__ __forceinline__ u16 f2bf(float f) {
    union { float f; u32 u; } v; v.f = f;
    u32 r = v.u + 0x7FFFu + ((v.u >> 16) & 1u);  // RNE
    return (u16)(r >> 16);
}

// global -> LDS direct copy, 16B per lane. LDS dest semantics: wave-uniform
// base + lane*16 (we pass each lane's natural pointer; layout is contiguous
// in lane order so both interpretations agree).
__device__ __forceinline__ void stage16(const u16* g, u16* lds_per_lane) {
#if __has_builtin(__builtin_amdgcn_global_load_lds)
    __builtin_amdgcn_global_load_lds((const __attribute__((address_space(1))) u32*)g,
                                     (__attribute__((address_space(3))) u32*)lds_per_lane,
                                     16, 0, 0);
#else
    *(uint4*)lds_per_lane = *(const uint4*)g;
#endif
}

// ---------------- fp32 -> bf16 conversion of X and Wq|Wk|Wv ----------------
__global__ __launch_bounds__(256) void convert_bf16(
    const float* __restrict__ X, const float* __restrict__ Wq,
    const float* __restrict__ Wk, const float* __restrict__ Wv,
    u16* __restrict__ Xb, u16* __restrict__ Wb)
{
    const int NX = MTOT * D_MODEL / 4;     // float4 count for X
    const int NW = D_MODEL * D_MODEL / 4;  // float4 count per W
    int i = blockIdx.x * 256 + threadIdx.x;
    if (i >= NX + 3 * NW) return;
    float4 v; u16* dst;
    if (i < NX)             { v = ((const float4*)X )[i];            dst = Xb + (size_t)i * 4; }
    else if (i < NX + NW)   { v = ((const float4*)Wq)[i - NX];       dst = Wb + (size_t)(i - NX) * 4; }
    else if (i < NX + 2*NW) { v = ((const float4*)Wk)[i - NX - NW];  dst = Wb + (size_t)NW * 4 + (size_t)(i - NX - NW) * 4; }
    else                    { v = ((const float4*)Wv)[i - NX - 2*NW];dst = Wb + (size_t)NW * 8 + (size_t)(i - NX - 2*NW) * 4; }
    ushort4 o;
    o.x = f2bf(v.x); o.y = f2bf(v.y); o.z = f2bf(v.z); o.w = f2bf(v.w);
    *(ushort4*)dst = o;
}

// ---------------- QKV projection: MFMA GEMM, y = Xb @ Wb^T + bias ----------
// 128x128 tile, BK=32, 4 waves (2x2), each wave 64x64 (4x4 MFMA tiles).
// Output written as bf16 in [B,H,S,DK].
__global__ __launch_bounds__(256, 2) void proj_mfma(
    const u16* __restrict__ Xb, const u16* __restrict__ Wb,
    const float* __restrict__ bq, const float* __restrict__ bk, const float* __restrict__ bv,
    u16* __restrict__ Qb, u16* __restrict__ Kb, u16* __restrict__ Vb)
{
    __shared__ u16 As[128 * 32];  // [m][k] rows of 32 bf16 (64 B), contiguous for global_load_lds
    __shared__ u16 Bs[128 * 32];  // [n][k]

    const int which = blockIdx.z;
    const u16* __restrict__ W = Wb + (size_t)which * D_MODEL * D_MODEL;
    const float* __restrict__ bias = which == 0 ? bq : (which == 1 ? bk : bv);
    u16* __restrict__ Out = which == 0 ? Qb : (which == 1 ? Kb : Vb);

    const int m0 = blockIdx.x * 128, n0 = blockIdx.y * 128;
    const int tid = threadIdx.x, lane = tid & 63, w = tid >> 6;
    const int quad = lane >> 4, l15 = lane & 15;
    const int wr = w >> 1, wc = w & 1;

    f32x4 acc[4][4];
#pragma unroll
    for (int i = 0; i < 4; i++)
#pragma unroll
        for (int j = 0; j < 4; j++) acc[i][j] = (f32x4)0.0f;

    const int srow = 32 * w + (lane >> 2);   // staging row within tile (per inst +16)
    const int scol = (lane & 3) * 8;         // element col within 32-wide k chunk

    for (int k0 = 0; k0 < D_MODEL; k0 += 32) {
#pragma unroll
        for (int t = 0; t < 2; t++) {
            stage16(Xb + (size_t)(m0 + srow + 16 * t) * D_MODEL + k0 + scol,
                    &As[(32 * w + 16 * t) * 32 + lane * 8]);
            stage16(W + (size_t)(n0 + srow + 16 * t) * D_MODEL + k0 + scol,
                    &Bs[(32 * w + 16 * t) * 32 + lane * 8]);
        }
        __syncthreads();
        bf16x8 af[4], bfr[4];
#pragma unroll
        for (int i = 0; i < 4; i++)
            af[i] = *(const bf16x8*)&As[(wr * 64 + i * 16 + l15) * 32 + quad * 8];
#pragma unroll
        for (int j = 0; j < 4; j++)
            bfr[j] = *(const bf16x8*)&Bs[(wc * 64 + j * 16 + l15) * 32 + quad * 8];
#pragma unroll
        for (int i = 0; i < 4; i++)
#pragma unroll
            for (int j = 0; j < 4; j++)
                acc[i][j] = __builtin_amdgcn_mfma_f32_16x16x32_bf16(af[i], bfr[j], acc[i][j], 0, 0, 0);
        __syncthreads();
    }

    float bj[4];
#pragma unroll
    for (int j = 0; j < 4; j++) bj[j] = bias[n0 + wc * 64 + j * 16 + l15];
#pragma unroll
    for (int i = 0; i < 4; i++) {
#pragma unroll
        for (int j = 0; j < 4; j++) {
#pragma unroll
            for (int r = 0; r < 4; r++) {
                int m = m0 + wr * 64 + i * 16 + quad * 4 + r;  // row = quad*4+reg
                int n = n0 + wc * 64 + j * 16 + l15;           // col = lane&15
                int b = m >> 11, s = m & (SEQ - 1);
                int h = n >> 6, d = n & 63;
                Out[(((size_t)b * NH + h) * SEQ + s) * DK + d] = f2bf(acc[i][j][r] + bj[j]);
            }
        }
    }
}

// ---------------- MFMA flash attention ----------------
// Block: 256 thr (4 waves), 128-row Q tile; KV chunks of 64 keys.
// Wave w owns q-rows [32w, 32w+32). Softmax reductions via shfl_xor (rows
// live across 16 lanes in C-layout). P -> LDS (A-layout) -> PV MFMA.
__global__ __launch_bounds__(256, 2) void attn_mfma(
    const u16* __restrict__ Qg, const u16* __restrict__ Kg, const u16* __restrict__ Vg,
    const int* __restrict__ mask, float* __restrict__ out)
{
    __shared__ u16 Ks[64 * 72];   // [key][dk]  pad 72: b128 reads land 2-way max
    __shared__ u16 Vt[64 * 72];   // [dk][key]  (V transposed: PV B-frag needs key-contiguous)
    __shared__ u16 Ps[128 * 72];  // [q][key]

    const int qt = blockIdx.x, h = blockIdx.y, b = blockIdx.z;
    const int tid = threadIdx.x, lane = tid & 63, w = tid >> 6;
    const int quad = lane >> 4, l15 = lane & 15;
    const size_t bh = (size_t)b * NH + h;
    const u16* __restrict__ Qp = Qg + (bh * SEQ + qt * 128) * DK;
    const u16* __restrict__ Kp = Kg + bh * SEQ * DK;
    const u16* __restrict__ Vp = Vg + bh * SEQ * DK;
    const int* __restrict__ mp = mask + b * SEQ;

    // persistent Q fragments (A-layout), straight from global
    bf16x8 qf[2][2];
#pragma unroll
    for (int tr = 0; tr < 2; tr++)
#pragma unroll
        for (int kk = 0; kk < 2; kk++)
            qf[tr][kk] = *(const bf16x8*)(Qp + (size_t)(32 * w + 16 * tr + l15) * DK + kk * 32 + quad * 8);

    f32x4 O[2][4];
    float mrow[2][4], lrow[2][4];
#pragma unroll
    for (int tr = 0; tr < 2; tr++)
#pragma unroll
        for (int n = 0; n < 4; n++) O[tr][n] = (f32x4)0.0f;
#pragma unroll
    for (int tr = 0; tr < 2; tr++)
#pragma unroll
        for (int r = 0; r < 4; r++) { mrow[tr][r] = -__builtin_huge_valf(); lrow[tr][r] = 0.0f; }

    const int lkey = tid & 63, ldk0 = (tid >> 6) * 16;  // loader mapping: 64 consecutive keys/wave-row

    for (int kt = 0; kt < SEQ / 64; kt++) {
        // --- stage K (straight) and V (transposed) ---
        {
            const u16* kr = Kp + (size_t)(kt * 64 + lkey) * DK + ldk0;
            bf16x8 k0 = *(const bf16x8*)kr, k1 = *(const bf16x8*)(kr + 8);
            *(bf16x8*)&Ks[lkey * 72 + ldk0] = k0;
            *(bf16x8*)&Ks[lkey * 72 + ldk0 + 8] = k1;
            const u16* vr = Vp + (size_t)(kt * 64 + lkey) * DK + ldk0;
            bf16x8 v0 = *(const bf16x8*)vr, v1 = *(const bf16x8*)(vr + 8);
#pragma unroll
            for (int ii = 0; ii < 8; ii++) Vt[(ldk0 + ii) * 72 + lkey] = (u16)v0[ii];
#pragma unroll
            for (int ii = 0; ii < 8; ii++) Vt[(ldk0 + 8 + ii) * 72 + lkey] = (u16)v1[ii];
        }
        int msk[4];
#pragma unroll
        for (int j = 0; j < 4; j++) msk[j] = mp[kt * 64 + j * 16 + l15];
        __syncthreads();

        // --- scores: S = Q K^T (per wave: 32 rows x 64 keys = 2x4 tiles) ---
        f32x4 S[2][4];
#pragma unroll
        for (int tr = 0; tr < 2; tr++)
#pragma unroll
            for (int j = 0; j < 4; j++) S[tr][j] = (f32x4)0.0f;
#pragma unroll
        for (int j = 0; j < 4; j++) {
            bf16x8 kf0 = *(const bf16x8*)&Ks[(j * 16 + l15) * 72 + quad * 8];
            bf16x8 kf1 = *(const bf16x8*)&Ks[(j * 16 + l15) * 72 + 32 + quad * 8];
#pragma unroll
            for (int tr = 0; tr < 2; tr++) {
                S[tr][j] = __builtin_amdgcn_mfma_f32_16x16x32_bf16(qf[tr][0], kf0, S[tr][j], 0, 0, 0);
                S[tr][j] = __builtin_amdgcn_mfma_f32_16x16x32_bf16(qf[tr][1], kf1, S[tr][j], 0, 0, 0);
            }
        }

        // --- scale + key mask ---
#pragma unroll
        for (int tr = 0; tr < 2; tr++)
#pragma unroll
            for (int j = 0; j < 4; j++)
#pragma unroll
                for (int r = 0; r < 4; r++)
                    S[tr][j][r] = msk[j] ? NEGV : S[tr][j][r] * 0.125f;

        // --- online softmax (row = quad*4+r, spans 16 lanes: shfl_xor over low 4 bits) ---
        float alpha[2][4];
#pragma unroll
        for (int tr = 0; tr < 2; tr++)
#pragma unroll
            for (int r = 0; r < 4; r++) {
                float mx = fmaxf(fmaxf(S[tr][0][r], S[tr][1][r]), fmaxf(S[tr][2][r], S[tr][3][r]));
                mx = fmaxf(mx, __shfl_xor(mx, 1));
                mx = fmaxf(mx, __shfl_xor(mx, 2));
                mx = fmaxf(mx, __shfl_xor(mx, 4));
                mx = fmaxf(mx, __shfl_xor(mx, 8));
                float mn = fmaxf(mrow[tr][r], mx);
                alpha[tr][r] = __expf(mrow[tr][r] - mn);  // first chunk: exp(-inf)=0
                mrow[tr][r] = mn;
            }
#pragma unroll
        for (int tr = 0; tr < 2; tr++)
#pragma unroll
            for (int j = 0; j < 4; j++)
#pragma unroll
                for (int r = 0; r < 4; r++)
                    S[tr][j][r] = __expf(S[tr][j][r] - mrow[tr][r]);
#pragma unroll
        for (int tr = 0; tr < 2; tr++)
#pragma unroll
            for (int r = 0; r < 4; r++) {
                float ls = S[tr][0][r] + S[tr][1][r] + S[tr][2][r] + S[tr][3][r];
                ls += __shfl_xor(ls, 1);
                ls += __shfl_xor(ls, 2);
                ls += __shfl_xor(ls, 4);
                ls += __shfl_xor(ls, 8);
                lrow[tr][r] = alpha[tr][r] * lrow[tr][r] + ls;
            }

        // --- P -> LDS (bf16, A-layout rows), rescale O ---
#pragma unroll
        for (int tr = 0; tr < 2; tr++)
#pragma unroll
            for (int j = 0; j < 4; j++)
#pragma unroll
                for (int r = 0; r < 4; r++)
                    Ps[(32 * w + 16 * tr + quad * 4 + r) * 72 + j * 16 + l15] = f2bf(S[tr][j][r]);
#pragma unroll
        for (int tr = 0; tr < 2; tr++)
#pragma unroll
            for (int n = 0; n < 4; n++)
#pragma unroll
                for (int r = 0; r < 4; r++)
                    O[tr][n][r] *= alpha[tr][r];
        __syncthreads();  // Ps visibility across lanes (cheap safety)

        // --- PV: O += P V ---
        bf16x8 pf[2][2];
#pragma unroll
        for (int tr = 0; tr < 2; tr++)
#pragma unroll
            for (int kk = 0; kk < 2; kk++)
                pf[tr][kk] = *(const bf16x8*)&Ps[(32 * w + 16 * tr + l15) * 72 + kk * 32 + quad * 8];
#pragma unroll
        for (int n = 0; n < 4; n++) {
            bf16x8 vf0 = *(const bf16x8*)&Vt[(n * 16 + l15) * 72 + quad * 8];
            bf16x8 vf1 = *(const bf16x8*)&Vt[(n * 16 + l15) * 72 + 32 + quad * 8];
#pragma unroll
            for (int tr = 0; tr < 2; tr++) {
                O[tr][n] = __builtin_amdgcn_mfma_f32_16x16x32_bf16(pf[tr][0], vf0, O[tr][n], 0, 0, 0);
                O[tr][n] = __builtin_amdgcn_mfma_f32_16x16x32_bf16(pf[tr][1], vf1, O[tr][n], 0, 0, 0);
            }
        }
        __syncthreads();  // protect Ks/Vt before next chunk's staging
    }

    // --- epilogue: normalize, write fp32 [B,S,D_MODEL] ---
#pragma unroll
    for (int tr = 0; tr < 2; tr++)
#pragma unroll
        for (int r = 0; r < 4; r++) {
            float inv = 1.0f / lrow[tr][r];
            int q = qt * 128 + 32 * w + 16 * tr + quad * 4 + r;
#pragma unroll
            for (int n = 0; n < 4; n++)
                out[((size_t)b * SEQ + q) * D_MODEL + h * DK + n * 16 + l15] = O[tr][n][r] * inv;
        }
}

extern "C" void kernel_launch(void* const* d_in, const int* in_sizes, int n_in,
                              void* d_out, int out_size, void* d_ws, size_t ws_size,
                              hipStream_t stream)
{
    const float* X  = (const float*)d_in[0];
    const int* mask = (const int*)d_in[1];
    const float* Wq = (const float*)d_in[2];
    const float* bq = (const float*)d_in[3];
    const float* Wk = (const float*)d_in[4];
    const float* bk = (const float*)d_in[5];
    const float* Wv = (const float*)d_in[6];
    const float* bv = (const float*)d_in[7];
    float* out = (float*)d_out;

    // workspace (bf16): Xb 8MB | Wb 6MB | Qb,Kb,Vb 8MB each = 38MB total
    u16* Xb = (u16*)d_ws;
    u16* Wb = Xb + (size_t)MTOT * D_MODEL;
    u16* Qb = Wb + (size_t)3 * D_MODEL * D_MODEL;
    u16* Kb = Qb + (size_t)BATCH * NH * SEQ * DK;
    u16* Vb = Kb + (size_t)BATCH * NH * SEQ * DK;

    const int ncvt = (MTOT * D_MODEL + 3 * D_MODEL * D_MODEL) / 4;
    convert_bf16<<<(ncvt + 255) / 256, 256, 0, stream>>>(X, Wq, Wk, Wv, Xb, Wb);
    proj_mfma<<<dim3(MTOT / 128, D_MODEL / 128, 3), 256, 0, stream>>>(Xb, Wb, bq, bk, bv, Qb, Kb, Vb);
    attn_mfma<<<dim3(SEQ / 128, NH, BATCH), 256, 0, stream>>>(Qb, Kb, Vb, mask, out);
}

// Round 3
// 185.777 us; speedup vs baseline: 10.9316x; 1.3332x over previous
//
#include <hip/hip_runtime.h>
#include <math.h>

#define D_MODEL 1024
#define NH 16
#define DK 64
#define SEQ 2048
#define BATCH 2
#define MTOT (BATCH * SEQ)

typedef unsigned short u16;
typedef unsigned int u32;
typedef short bf16x8 __attribute__((ext_vector_type(8)));   // 8 bf16 = 4 VGPR (K=32 A/B frag)
typedef short bf16x4 __attribute__((ext_vector_type(4)));   // 4 bf16 = 2 VGPR (K=16 A/B frag)
typedef float f32x4 __attribute__((ext_vector_type(4)));    // C/D frag

static constexpr float NEGV = -1e8f;

__device__ __forceinline__ u16 f2bf(float f) {
    union { float f; u32 u; } v; v.f = f;
    u32 r = v.u + 0x7FFFu + ((v.u >> 16) & 1u);  // RNE
    return (u16)(r >> 16);
}

__device__ __forceinline__ f32x4 mfma16(bf16x4 a, bf16x4 b, f32x4 c) {
#if __has_builtin(__builtin_amdgcn_mfma_f32_16x16x16_bf16)
    return __builtin_amdgcn_mfma_f32_16x16x16_bf16(a, b, c, 0, 0, 0);
#else
    return __builtin_amdgcn_mfma_f32_16x16x16bf16_1k(a, b, c, 0, 0, 0);
#endif
}

__device__ __forceinline__ void stage16(const u16* g, u16* lds_per_lane) {
#if __has_builtin(__builtin_amdgcn_global_load_lds)
    __builtin_amdgcn_global_load_lds((const __attribute__((address_space(1))) u32*)g,
                                     (__attribute__((address_space(3))) u32*)lds_per_lane,
                                     16, 0, 0);
#else
    *(uint4*)lds_per_lane = *(const uint4*)g;
#endif
}

// ---------------- fp32 -> bf16 conversion of X and Wq|Wk|Wv ----------------
__global__ __launch_bounds__(256) void convert_bf16(
    const float* __restrict__ X, const float* __restrict__ Wq,
    const float* __restrict__ Wk, const float* __restrict__ Wv,
    u16* __restrict__ Xb, u16* __restrict__ Wb)
{
    const int NX = MTOT * D_MODEL / 4;
    const int NW = D_MODEL * D_MODEL / 4;
    int i = blockIdx.x * 256 + threadIdx.x;
    if (i >= NX + 3 * NW) return;
    float4 v; u16* dst;
    if (i < NX)             { v = ((const float4*)X )[i];            dst = Xb + (size_t)i * 4; }
    else if (i < NX + NW)   { v = ((const float4*)Wq)[i - NX];       dst = Wb + (size_t)(i - NX) * 4; }
    else if (i < NX + 2*NW) { v = ((const float4*)Wk)[i - NX - NW];  dst = Wb + (size_t)NW * 4 + (size_t)(i - NX - NW) * 4; }
    else                    { v = ((const float4*)Wv)[i - NX - 2*NW];dst = Wb + (size_t)NW * 8 + (size_t)(i - NX - 2*NW) * 4; }
    ushort4 o;
    o.x = f2bf(v.x); o.y = f2bf(v.y); o.z = f2bf(v.z); o.w = f2bf(v.w);
    *(ushort4*)dst = o;
}

// ---------------- QKV projection: MFMA GEMM, y = Xb @ Wb^T + bias ----------
__global__ __launch_bounds__(256, 2) void proj_mfma(
    const u16* __restrict__ Xb, const u16* __restrict__ Wb,
    const float* __restrict__ bq, const float* __restrict__ bk, const float* __restrict__ bv,
    u16* __restrict__ Qb, u16* __restrict__ Kb, u16* __restrict__ Vb)
{
    __shared__ u16 As[128 * 32];
    __shared__ u16 Bs[128 * 32];

    const int which = blockIdx.z;
    const u16* __restrict__ W = Wb + (size_t)which * D_MODEL * D_MODEL;
    const float* __restrict__ bias = which == 0 ? bq : (which == 1 ? bk : bv);
    u16* __restrict__ Out = which == 0 ? Qb : (which == 1 ? Kb : Vb);

    const int m0 = blockIdx.x * 128, n0 = blockIdx.y * 128;
    const int tid = threadIdx.x, lane = tid & 63, w = tid >> 6;
    const int quad = lane >> 4, l15 = lane & 15;
    const int wr = w >> 1, wc = w & 1;

    f32x4 acc[4][4];
#pragma unroll
    for (int i = 0; i < 4; i++)
#pragma unroll
        for (int j = 0; j < 4; j++) acc[i][j] = (f32x4)0.0f;

    const int srow = 32 * w + (lane >> 2);
    const int scol = (lane & 3) * 8;

    for (int k0 = 0; k0 < D_MODEL; k0 += 32) {
#pragma unroll
        for (int t = 0; t < 2; t++) {
            stage16(Xb + (size_t)(m0 + srow + 16 * t) * D_MODEL + k0 + scol,
                    &As[(32 * w + 16 * t) * 32 + lane * 8]);
            stage16(W + (size_t)(n0 + srow + 16 * t) * D_MODEL + k0 + scol,
                    &Bs[(32 * w + 16 * t) * 32 + lane * 8]);
        }
        __syncthreads();
        bf16x8 af[4], bfr[4];
#pragma unroll
        for (int i = 0; i < 4; i++)
            af[i] = *(const bf16x8*)&As[(wr * 64 + i * 16 + l15) * 32 + quad * 8];
#pragma unroll
        for (int j = 0; j < 4; j++)
            bfr[j] = *(const bf16x8*)&Bs[(wc * 64 + j * 16 + l15) * 32 + quad * 8];
#pragma unroll
        for (int i = 0; i < 4; i++)
#pragma unroll
            for (int j = 0; j < 4; j++)
                acc[i][j] = __builtin_amdgcn_mfma_f32_16x16x32_bf16(af[i], bfr[j], acc[i][j], 0, 0, 0);
        __syncthreads();
    }

    float bj[4];
#pragma unroll
    for (int j = 0; j < 4; j++) bj[j] = bias[n0 + wc * 64 + j * 16 + l15];
#pragma unroll
    for (int i = 0; i < 4; i++) {
#pragma unroll
        for (int j = 0; j < 4; j++) {
#pragma unroll
            for (int r = 0; r < 4; r++) {
                int m = m0 + wr * 64 + i * 16 + quad * 4 + r;
                int n = n0 + wc * 64 + j * 16 + l15;
                int b = m >> 11, s = m & (SEQ - 1);
                int h = n >> 6, d = n & 63;
                Out[(((size_t)b * NH + h) * SEQ + s) * DK + d] = f2bf(acc[i][j][r] + bj[j]);
            }
        }
    }
}

// ---------------- MFMA flash attention (transposed-score scheme) ----------
// S^T = K Q^T via 16x16x32 (A=K rows, B=Q rows, both layout-natural).
// P^T lands in C-layout == B-frag layout of 16x16x16 => O^T = V^T P^T with
// zero LDS round-trip for P. K/V double-buffered, 1 barrier/chunk.
__global__ __launch_bounds__(256, 2) void attn_mfma(
    const u16* __restrict__ Qg, const u16* __restrict__ Kg, const u16* __restrict__ Vg,
    const int* __restrict__ mask, float* __restrict__ out)
{
    constexpr int PADK = 72, PADV = 72;
    __shared__ u16 Ks[2][64 * PADK];   // [key][dk], straight
    __shared__ u16 Vt[2][64 * PADV];   // [dk][key], transposed
    __shared__ float mads[SEQ];        // per-key mask addend (0 or NEGV)

    const int qt0 = blockIdx.x, h = blockIdx.y, b = blockIdx.z;
    const int tid = threadIdx.x, lane = tid & 63, w = tid >> 6;
    const int quad = lane >> 4, l15 = lane & 15;
    const size_t bh = (size_t)b * NH + h;
    const u16* __restrict__ Qp = Qg + (bh * SEQ + qt0 * 128) * DK;
    const u16* __restrict__ Kp = Kg + bh * SEQ * DK;
    const u16* __restrict__ Vp = Vg + bh * SEQ * DK;
    const int* __restrict__ mp = mask + b * SEQ;

    // mask addend table
    for (int i = tid; i < SEQ; i += 256) mads[i] = mp[i] ? NEGV : 0.0f;

    // persistent Q fragments (B operand): B[k=dk][n=q], n=l15, k=quad*8+j
    const int q0 = w * 32;
    bf16x8 qf[2][2];
#pragma unroll
    for (int qt = 0; qt < 2; qt++)
#pragma unroll
        for (int half = 0; half < 2; half++)
            qf[qt][half] = *(const bf16x8*)(Qp + (size_t)(q0 + qt * 16 + l15) * DK + half * 32 + quad * 8);

    // staging index maps
    const int skey = tid & 63, sdk = (tid >> 6) * 16;       // K loader
    const int vkp2 = (tid & 31) * 2, vd0 = (tid >> 5) * 8;  // V loader (2 keys x 8 dk)

    // stage chunk 0 into buffer 0
    {
        const u16* kr = Kp + (size_t)skey * DK + sdk;
        bf16x8 k0 = *(const bf16x8*)kr, k1 = *(const bf16x8*)(kr + 8);
        u16* kd = &Ks[0][skey * PADK + sdk];
        *(bf16x8*)kd = k0; *(bf16x8*)(kd + 8) = k1;
        const u16* vr = Vp + (size_t)vkp2 * DK + vd0;
        bf16x8 v0 = *(const bf16x8*)vr, v1 = *(const bf16x8*)(vr + DK);
#pragma unroll
        for (int i = 0; i < 8; i++)
            *(u32*)&Vt[0][(vd0 + i) * PADV + vkp2] = (u32)(u16)v0[i] | ((u32)(u16)v1[i] << 16);
    }
    __syncthreads();

    f32x4 O[4][2];    // O^T: [d-tile][q-tile], d=quad*4+r, q=l15
    float mrow[2], lrow[2];
#pragma unroll
    for (int dt = 0; dt < 4; dt++)
#pragma unroll
        for (int qt = 0; qt < 2; qt++) O[dt][qt] = (f32x4)0.0f;
    mrow[0] = mrow[1] = -__builtin_huge_valf();
    lrow[0] = lrow[1] = 0.0f;

    for (int kt = 0; kt < SEQ / 64; kt++) {
        const int bb = kt & 1;
        // prefetch next chunk (global -> regs)
        bf16x8 nk0, nk1, nv0, nv1;
        if (kt < SEQ / 64 - 1) {
            const u16* kr = Kp + (size_t)((kt + 1) * 64 + skey) * DK + sdk;
            nk0 = *(const bf16x8*)kr; nk1 = *(const bf16x8*)(kr + 8);
            const u16* vr = Vp + (size_t)((kt + 1) * 64 + vkp2) * DK + vd0;
            nv0 = *(const bf16x8*)vr; nv1 = *(const bf16x8*)(vr + DK);
        }

        // --- S^T = K Q^T: [4 key-tiles][2 q-tiles], key=quad*4+r, q=l15 ---
        f32x4 St[4][2];
#pragma unroll
        for (int ktl = 0; ktl < 4; ktl++) {
            bf16x8 kf0 = *(const bf16x8*)&Ks[bb][(ktl * 16 + l15) * PADK + quad * 8];
            bf16x8 kf1 = *(const bf16x8*)&Ks[bb][(ktl * 16 + l15) * PADK + 32 + quad * 8];
#pragma unroll
            for (int qt = 0; qt < 2; qt++) {
                f32x4 acc = (f32x4)0.0f;
                acc = __builtin_amdgcn_mfma_f32_16x16x32_bf16(kf0, qf[qt][0], acc, 0, 0, 0);
                acc = __builtin_amdgcn_mfma_f32_16x16x32_bf16(kf1, qf[qt][1], acc, 0, 0, 0);
                St[ktl][qt] = acc;
            }
        }

        // --- scale + mask (fma with precomputed addend, b128 broadcast) ---
#pragma unroll
        for (int ktl = 0; ktl < 4; ktl++) {
            f32x4 ma = *(const f32x4*)&mads[kt * 64 + ktl * 16 + quad * 4];
#pragma unroll
            for (int qt = 0; qt < 2; qt++)
#pragma unroll
                for (int r = 0; r < 4; r++)
                    St[ktl][qt][r] = St[ktl][qt][r] * 0.125f + ma[r];
        }

        // --- online softmax along columns (q=l15 lane-local; rows span regs+quads) ---
        float alpha[2];
#pragma unroll
        for (int qt = 0; qt < 2; qt++) {
            float mx = St[0][qt][0];
#pragma unroll
            for (int ktl = 0; ktl < 4; ktl++)
#pragma unroll
                for (int r = 0; r < 4; r++) mx = fmaxf(mx, St[ktl][qt][r]);
            mx = fmaxf(mx, __shfl_xor(mx, 16));
            mx = fmaxf(mx, __shfl_xor(mx, 32));
            float mn = fmaxf(mrow[qt], mx);
            alpha[qt] = __expf(mrow[qt] - mn);
            mrow[qt] = mn;
            float sum = 0.0f;
#pragma unroll
            for (int ktl = 0; ktl < 4; ktl++)
#pragma unroll
                for (int r = 0; r < 4; r++) {
                    float p = __expf(St[ktl][qt][r] - mn);
                    St[ktl][qt][r] = p;
                    sum += p;
                }
            sum += __shfl_xor(sum, 16);
            sum += __shfl_xor(sum, 32);
            lrow[qt] = alpha[qt] * lrow[qt] + sum;
        }

        // --- pack P^T to bf16 (already in B-frag layout for 16x16x16) ---
        bf16x4 pf[4][2];
#pragma unroll
        for (int ktl = 0; ktl < 4; ktl++)
#pragma unroll
            for (int qt = 0; qt < 2; qt++) {
                bf16x4 pp;
#pragma unroll
                for (int r = 0; r < 4; r++) pp[r] = (short)f2bf(St[ktl][qt][r]);
                pf[ktl][qt] = pp;
            }

        // --- rescale O ---
#pragma unroll
        for (int dt = 0; dt < 4; dt++)
#pragma unroll
            for (int qt = 0; qt < 2; qt++)
#pragma unroll
                for (int r = 0; r < 4; r++) O[dt][qt][r] *= alpha[qt];

        // --- O^T += V^T P^T (16x16x16; A=V^T b64 reads from Vt) ---
#pragma unroll
        for (int ktl = 0; ktl < 4; ktl++)
#pragma unroll
            for (int dt = 0; dt < 4; dt++) {
                bf16x4 vf = *(const bf16x4*)&Vt[bb][(dt * 16 + l15) * PADV + ktl * 16 + quad * 4];
#pragma unroll
                for (int qt = 0; qt < 2; qt++)
                    O[dt][qt] = mfma16(vf, pf[ktl][qt], O[dt][qt]);
            }

        // --- write prefetched chunk into the other buffer ---
        if (kt < SEQ / 64 - 1) {
            u16* kd = &Ks[bb ^ 1][skey * PADK + sdk];
            *(bf16x8*)kd = nk0; *(bf16x8*)(kd + 8) = nk1;
#pragma unroll
            for (int i = 0; i < 8; i++)
                *(u32*)&Vt[bb ^ 1][(vd0 + i) * PADV + vkp2] = (u32)(u16)nv0[i] | ((u32)(u16)nv1[i] << 16);
        }
        __syncthreads();
    }

    // --- epilogue: normalize, write fp32 [B,S,D_MODEL] ---
    float inv[2] = {1.0f / lrow[0], 1.0f / lrow[1]};
#pragma unroll
    for (int qt = 0; qt < 2; qt++) {
        int q = qt0 * 128 + q0 + qt * 16 + l15;
        float* op = out + ((size_t)b * SEQ + q) * D_MODEL + h * DK;
#pragma unroll
        for (int dt = 0; dt < 4; dt++)
#pragma unroll
            for (int r = 0; r < 4; r++)
                op[dt * 16 + quad * 4 + r] = O[dt][qt][r] * inv[qt];
    }
}

extern "C" void kernel_launch(void* const* d_in, const int* in_sizes, int n_in,
                              void* d_out, int out_size, void* d_ws, size_t ws_size,
                              hipStream_t stream)
{
    const float* X  = (const float*)d_in[0];
    const int* mask = (const int*)d_in[1];
    const float* Wq = (const float*)d_in[2];
    const float* bq = (const float*)d_in[3];
    const float* Wk = (const float*)d_in[4];
    const float* bk = (const float*)d_in[5];
    const float* Wv = (const float*)d_in[6];
    const float* bv = (const float*)d_in[7];
    float* out = (float*)d_out;

    u16* Xb = (u16*)d_ws;
    u16* Wb = Xb + (size_t)MTOT * D_MODEL;
    u16* Qb = Wb + (size_t)3 * D_MODEL * D_MODEL;
    u16* Kb = Qb + (size_t)BATCH * NH * SEQ * DK;
    u16* Vb = Kb + (size_t)BATCH * NH * SEQ * DK;

    const int ncvt = (MTOT * D_MODEL + 3 * D_MODEL * D_MODEL) / 4;
    convert_bf16<<<(ncvt + 255) / 256, 256, 0, stream>>>(X, Wq, Wk, Wv, Xb, Wb);
    proj_mfma<<<dim3(MTOT / 128, D_MODEL / 128, 3), 256, 0, stream>>>(Xb, Wb, bq, bk, bv, Qb, Kb, Vb);
    attn_mfma<<<dim3(SEQ / 128, NH, BATCH), 256, 0, stream>>>(Qb, Kb, Vb, mask, out);
}